// Round 17
// baseline (585.398 us; speedup 1.0000x reference)
//
#include <hip/hip_runtime.h>
#include <hip/hip_bf16.h>

#define NN 131072   // total nodes (1024 graphs x 128)
#define NG 1024     // graphs
#define NE 1048576  // edges per edge set
#define EB 16384    // edges per binning block
#define NB 64       // binning blocks per set (NE/EB)
#define EMAX 1536   // per-graph edge cap (mean 1024, sigma 32 -> +16 sigma)

typedef __hip_bfloat16 bf16;
typedef __attribute__((ext_vector_type(8))) short short8v;
typedef __attribute__((ext_vector_type(4))) float f32x4;

__device__ __forceinline__ float b2f(bf16 v){ return __bfloat162float(v); }
__device__ __forceinline__ bf16 f2b(float v){ return __float2bfloat16(v); }
__device__ __forceinline__ unsigned short f2bu(float v){ bf16 b = f2b(v); return *(unsigned short*)&b; }
__device__ __forceinline__ float eluf(float x){ return x > 0.f ? x : expm1f(x); }
__device__ __forceinline__ float lrelu(float x){ return x >= 0.f ? x : 0.2f*x; }

__device__ __forceinline__ float ldx(const void* p, size_t i, int f){
  return f ? ((const float*)p)[i] : b2f(((const bf16*)p)[i]);
}

struct EPtrs { const int *s0,*d0,*s1,*d1,*s2,*d2,*s3,*d3; };

// ---------------- input dtype probe (validated round 4) ----------------
__global__ void detect_dtype(const unsigned short* __restrict__ x, int* __restrict__ flag){
  if (blockIdx.x==0 && threadIdx.x==0){
    int bad = 0;
    for (int i=0;i<2048;i++){
      unsigned short e = (x[i] >> 7) & 0xFF;
      if (e == 0xFF) bad++;
      else if (e >= 0x90) bad++;
      else if (e != 0 && e < 0x60) bad++;
    }
    *flag = (bad > 64) ? 1 : 0;
  }
}

// ---------------- CSR build (validated round 7): block-aggregated graph binning ----------------
__global__ __launch_bounds__(256) void hist_bagg(EPtrs ep, int* __restrict__ Hb){
  __shared__ int cnt[NG];
  int set = blockIdx.y, blk = blockIdx.x, t = threadIdx.x;
  const int* dp = set==0 ? ep.d0 : set==1 ? ep.d1 : set==2 ? ep.d2 : ep.d3;
  for (int i=t;i<NG;i+=256) cnt[i]=0;
  __syncthreads();
  int e0 = blk*EB;
  for (int i=t;i<EB;i+=256) atomicAdd(&cnt[dp[e0+i]>>7],1);
  __syncthreads();
  for (int i=t;i<NG;i+=256) Hb[((size_t)set*NB+blk)*NG+i] = cnt[i];
}

__global__ __launch_bounds__(1024) void scan_bagg(const int* __restrict__ Hb, int* __restrict__ Bb,
                                                  int* __restrict__ base_gs){
  __shared__ int sh[1024];
  int set = blockIdx.x, t = threadIdx.x;
  int run = 0;
  for (int b=0;b<NB;b++){
    int v = Hb[((size_t)set*NB + b)*NG + t];
    Bb[((size_t)set*NB + b)*NG + t] = run;
    run += v;
  }
  int val = run; sh[t] = run; __syncthreads();
  for (int d=1; d<1024; d<<=1){
    int add = (t>=d)? sh[t-d] : 0; __syncthreads();
    val += add; sh[t] = val; __syncthreads();
  }
  int binbase = val - run;
  base_gs[set*(NG+1) + t] = binbase;
  if (t==1023) base_gs[set*(NG+1)+NG] = val;   // == NE
  for (int b=0;b<NB;b++) Bb[((size_t)set*NB + b)*NG + t] += binbase;
}

__global__ __launch_bounds__(256) void scatter_bagg(EPtrs ep, const int* __restrict__ Bb,
                                                    unsigned short* __restrict__ pk){
  __shared__ int cur[NG];
  int set = blockIdx.y, blk = blockIdx.x, t = threadIdx.x;
  const int* sp = set==0 ? ep.s0 : set==1 ? ep.s1 : set==2 ? ep.s2 : ep.s3;
  const int* dp = set==0 ? ep.d0 : set==1 ? ep.d1 : set==2 ? ep.d2 : ep.d3;
  for (int i=t;i<NG;i+=256) cur[i] = Bb[((size_t)set*NB+blk)*NG+i];
  __syncthreads();
  int e0 = blk*EB;
  for (int i=t;i<EB;i+=256){
    int e = e0+i;
    int d = dp[e], s = sp[e];
    int p = atomicAdd(&cur[d>>7],1);
    pk[(size_t)set*NE + p] = (unsigned short)(((d & 127) << 8) | (s & 127));
  }
}

__global__ __launch_bounds__(256) void build_csr(const unsigned short* __restrict__ pk, const int* __restrict__ base,
                                                 unsigned char* __restrict__ srcs8, int* __restrict__ offs4){
  __shared__ int hist[128], excl[128], cur[128];
  __shared__ unsigned char ob[8192];
  int set = blockIdx.y, g = blockIdx.x, t = threadIdx.x;
  int n0 = base[set*(NG+1) + g], n1 = base[set*(NG+1) + g + 1];
  int cnt = min(n1 - n0, 8192);
  if (t < 128) hist[t] = 0;
  __syncthreads();
  const unsigned short* PK = pk + (size_t)set*NE + n0;
  for (int i=t; i<cnt; i+=256) atomicAdd(&hist[PK[i]>>8], 1);
  __syncthreads();
  if (t < 128) excl[t] = hist[t];
  __syncthreads();
  for (int d=1; d<128; d<<=1){
    int v = (t < 128 && t >= d) ? excl[t-d] : 0;
    __syncthreads();
    if (t < 128) excl[t] += v;
    __syncthreads();
  }
  if (t < 128){
    int e_ = excl[t] - hist[t];
    cur[t] = e_;
    offs4[(size_t)set*(NN+1) + g*128 + t] = n0 + e_;
  }
  if (g == NG-1 && t == 0) offs4[(size_t)set*(NN+1) + NN] = NE;
  __syncthreads();
  for (int i=t; i<cnt; i+=256){
    unsigned short v = PK[i];
    int p = atomicAdd(&cur[v>>8], 1);
    ob[p] = (unsigned char)(v & 127);
  }
  __syncthreads();
  unsigned char* S = srcs8 + (size_t)set*NE + n0;
  for (int i=t; i<cnt; i+=256) S[i] = ob[i];
}

// ---------------- weight prep (validated rounds 4/8) ----------------
// sm: 0 att_is[64] | 64 att_id[64] | 128 att_xs[64] | 192 att_ps[128] | 320 att_pd[128] |
//     448 b_intra[64] | 512 b_inter[64] | 576 b_pool[128] | 704 ln_w[128] | 832 ln_b[128]
__global__ __launch_bounds__(256) void prep_kernel(
    const void* w_intra, const void* w_isrc, const void* w_idst, const void* att_xd, const void* w_pool,
    const void* att_is, const void* att_id, const void* att_xs,
    const void* att_ps, const void* att_pd,
    const void* b_intra, const void* b_inter, const void* b_pool,
    const void* ln_w, const void* ln_b,
    bf16* __restrict__ Wtc, bf16* __restrict__ Wtp, float* __restrict__ vdst, float* __restrict__ sm,
    const int* __restrict__ fp){
  int f = *fp;
  int t = threadIdx.x;
  for (int i=t; i<16384; i+=256){
    int j = i & 7, l = (i>>3) & 63, ks = (i>>9) & 3, nt = i >> 11;
    int k = ks*32 + ((l>>4)<<3) + j;
    int c = nt*16 + (l & 15);
    float w1 = (c < 64) ? ldx(w_intra, k*64 + c, f) : ldx(w_isrc, k*64 + (c-64), f);
    Wtc[i] = f2b(w1);
    Wtp[i] = f2b(ldx(w_pool, k*128 + c, f));
  }
  {
    int k = t>>1, h = t&1; float a = 0.f;
    for (int c=0;c<32;c++) a += ldx(w_idst, k*64 + h*32 + c, f) * ldx(att_xd, h*32 + c, f);
    vdst[t] = a;
  }
  if (t < 64){
    sm[t]     = ldx(att_is, t, f);
    sm[64+t]  = ldx(att_id, t, f);
    sm[128+t] = ldx(att_xs, t, f);
    sm[448+t] = ldx(b_intra, t, f);
    sm[512+t] = ldx(b_inter, t, f);
  }
  if (t < 128){
    sm[192+t] = ldx(att_ps, t, f);
    sm[320+t] = ldx(att_pd, t, f);
    sm[576+t] = ldx(b_pool, t, f);
    sm[704+t] = ldx(ln_w, t, f);
    sm[832+t] = ldx(ln_b, t, f);
  }
}

// ---------------- inter-dst logits from raw input (folded W_dst@att_dst) ----------------
__global__ __launch_bounds__(256) void avec_dx_m(const void* Xh, const void* Xt, const float* __restrict__ vdst,
                                                 float* __restrict__ aDx_h, float* __restrict__ aDx_t,
                                                 const int* __restrict__ fp){
  int f = *fp;
  int gid = blockIdx.x*256 + threadIdx.x;
  int n = gid >> 6, lane = gid & 63;
  int side = n >= NN;
  const void* X = side ? Xt : Xh;
  float* aDx = side ? aDx_t : aDx_h;
  int nl = side ? n - NN : n;
  float x1 = eluf(ldx(X, (size_t)nl*128 + lane, f));
  float x2 = eluf(ldx(X, (size_t)nl*128 + 64 + lane, f));
  float t0 = x1*vdst[lane*2+0] + x2*vdst[(lane+64)*2+0];
  float t1 = x1*vdst[lane*2+1] + x2*vdst[(lane+64)*2+1];
  #pragma unroll
  for (int o=32;o;o>>=1){ t0 += __shfl_xor(t0,o); t1 += __shfl_xor(t1,o); }
  if (lane == 0){ aDx[nl*2+0] = t0; aDx[nl*2+1] = t1; }
}

// ---------------- layer-1 fused: quarter-GEMM + logits + GAT (per set) ----------------
// Each (g,set) block: acc = elu(X_g) @ Wtc[half] (16 MFMAs/wave), logits from acc,
// Ft from acc regs, dense-P build (v6), PV MFMA, write rep (ws, bf16).
struct L1Set {
  const int* offs;
  const unsigned char* srcs;
  int a_side;       // 0: h_x, 1: t_x
  int wt_half;      // 0: cols 0-63 (nt 0-3), 1: cols 64-127 (nt 4-7)
  int att_mode;     // 0: intra (att_is/att_id, self-loops), 1: inter (att_xs, aD from aDx)
  int col_off;      // output col offset in rep target
  const float* aDx; // att_mode 1 only
  bf16* repout;     // rep_h or rep_t (ws)
};
struct L1Set4 { L1Set s[4]; };

__global__ __launch_bounds__(512) void gat_l1(L1Set4 sets, const void* Xh, const void* Xt,
    const bf16* __restrict__ Wtc, const float* __restrict__ sm, const int* __restrict__ fp){
  __shared__ char U[34816];          // WtL-half (16 KB) then Pm 128x136 (34 KB)
  __shared__ bf16 Ft[32*136];        // per-head transposed feats from acc
  __shared__ float atab[192];        // 0-63 aS-table, 64-127 att_id, 128-191 bias
  __shared__ float2 aSl[128], aDl[128];
  __shared__ float rsum[128];
  __shared__ unsigned char ss[EMAX];
  __shared__ int begs[129];
  const L1Set S = sets.s[blockIdx.y];
  int g = blockIdx.x, t = threadIdx.x;
  int f = *fp;
  const void* A = S.a_side ? Xt : Xh;

  bf16* WtL = (bf16*)U;
  {
    const short8v* src = (const short8v*)(Wtc + (size_t)S.wt_half*8192);
    short8v* dst = (short8v*)WtL;
    #pragma unroll
    for (int i=0;i<2;i++) dst[t + i*512] = src[t + i*512];
  }
  if (t < 129) begs[t] = S.offs[g*128 + t];
  if (t < 192){
    float v;
    if (t < 64) v = sm[(S.att_mode ? 128 : 0) + t];
    else if (t < 128) v = sm[64 + (t-64)];
    else v = sm[(S.att_mode ? 512 : 448) + (t-128)];
    atab[t] = v;
  }
  __syncthreads();
  int gbeg = begs[0], Eg = min(begs[128]-gbeg, EMAX);
  for (int i=t; i<Eg; i+=512) ss[i] = S.srcs[gbeg + i];

  int w = t>>6, l = t&63, lr = l&15, lg = l>>4;
  size_t row = (size_t)g*128 + w*16 + lr;
  f32x4 acc[4];
  #pragma unroll
  for (int nt=0;nt<4;nt++) acc[nt] = (f32x4){0.f,0.f,0.f,0.f};
  #pragma unroll
  for (int ks=0;ks<4;ks++){
    short8v af;
    size_t ab = row*128 + ks*32 + lg*8;
    if (f){
      const float* Af = (const float*)A;
      #pragma unroll
      for (int j=0;j<8;j++){ ((unsigned short*)&af)[j] = f2bu(eluf(Af[ab+j])); }
    } else {
      const unsigned short* Au = (const unsigned short*)A;
      short8v raw = *(const short8v*)(Au + ab);
      #pragma unroll
      for (int j=0;j<8;j++){
        bf16 b; *(unsigned short*)&b = ((unsigned short*)&raw)[j];
        ((unsigned short*)&af)[j] = f2bu(eluf(b2f(b)));
      }
    }
    #pragma unroll
    for (int nt=0;nt<4;nt++){
      short8v bfr = *(const short8v*)((const unsigned short*)WtL + (size_t)((nt*4+ks)*64 + l)*8);
      acc[nt] = __builtin_amdgcn_mfma_f32_16x16x32_bf16(af, bfr, acc[nt], 0, 0, 0);
    }
  }
  // logits from acc: c = nt*16+lr in 0..63; head = c>>5 (nt<2 -> head0)
  #pragma unroll
  for (int rg=0; rg<4; ++rg){
    float pS0=0.f,pS1=0.f,pD0=0.f,pD1=0.f;
    #pragma unroll
    for (int nt=0;nt<4;nt++){
      float v = acc[nt][rg];
      int c = nt*16 + lr;
      float a = atab[c], b = atab[64+c];
      if (nt<2){ pS0 += v*a; pD0 += v*b; } else { pS1 += v*a; pD1 += v*b; }
    }
    #pragma unroll
    for (int o=1;o<16;o<<=1){
      pS0+=__shfl_xor(pS0,o); pS1+=__shfl_xor(pS1,o);
      pD0+=__shfl_xor(pD0,o); pD1+=__shfl_xor(pD1,o);
    }
    if (lr == 0){
      int rr = w*16 + lg*4 + rg;
      aSl[rr] = make_float2(pS0, pS1);
      if (S.att_mode == 0) aDl[rr] = make_float2(pD0, pD1);
    }
  }
  if (S.att_mode == 1 && t < 128) aDl[t] = ((const float2*)S.aDx)[g*128 + t];
  __syncthreads();   // aSl/aDl/ss ready; WtL dead

  bf16* Pm = (bf16*)U;
  #pragma unroll
  for (int h=0; h<2; ++h){
    for (int i=t; i<128*68; i+=512) ((unsigned int*)Pm)[i] = 0;
    // Ft from acc regs: head h -> nt {2h,2h+1}; Ft[c_local][k], c_local = ntl*16+lr
    #pragma unroll
    for (int ntl=0; ntl<2; ++ntl){
      int nt = h*2 + ntl;
      #pragma unroll
      for (int rg=0; rg<4; ++rg)
        ((unsigned short*)Ft)[(ntl*16+lr)*136 + (w*16+lg*4+rg)] = f2bu(acc[nt][rg]);
    }
    __syncthreads();
    if (t < 128){
      int r = t;
      float ad = h ? aDl[r].y : aDl[r].x;
      int b = begs[r]-gbeg, e = min(begs[r+1]-gbeg, EMAX);
      float rs = 0.f;
      unsigned short* Pr = (unsigned short*)Pm + r*136;
      for (int j=b; j<e; ++j){
        int s = ss[j];
        float as = h ? aSl[s].y : aSl[s].x;
        float p = __expf(lrelu(as + ad));
        bf16 ov; *(unsigned short*)&ov = Pr[s];
        Pr[s] = f2bu(b2f(ov) + p);
        rs += p;
      }
      if (S.att_mode == 0){
        float as = h ? aSl[r].y : aSl[r].x;
        float p = __expf(lrelu(as + ad));
        bf16 ov; *(unsigned short*)&ov = Pr[r];
        Pr[r] = f2bu(b2f(ov) + p);
        rs += p;
      }
      rsum[r] = rs;
    }
    __syncthreads();
    // PV: NT=2 per head
    f32x4 a2[2];
    a2[0] = (f32x4){0.f,0.f,0.f,0.f}; a2[1] = (f32x4){0.f,0.f,0.f,0.f};
    #pragma unroll
    for (int ks=0;ks<4;ks++){
      short8v af = *(const short8v*)((const unsigned short*)Pm + (w*16+lr)*136 + ks*32 + lg*8);
      #pragma unroll
      for (int j=0;j<2;j++){
        short8v bfr = *(const short8v*)((const unsigned short*)Ft + (j*16+lr)*136 + ks*32 + lg*8);
        a2[j] = __builtin_amdgcn_mfma_f32_16x16x32_bf16(af, bfr, a2[j], 0, 0, 0);
      }
    }
    #pragma unroll
    for (int rg=0; rg<4; ++rg){
      int rrow = w*16 + lg*4 + rg;
      float rinv = 1.f / (rsum[rrow] + 1e-16f);
      size_t n = (size_t)g*128 + rrow;
      #pragma unroll
      for (int j=0;j<2;j++){
        int c = h*32 + j*16 + lr;
        float o = a2[j][rg]*rinv + atab[128+c];
        S.repout[n*128 + S.col_off + c] = f2b(o);
      }
    }
    __syncthreads();
  }
}

// ---------------- pool fused: full GEMM + logits + GAT, write d_out (flag) + gathers ----------------
__global__ __launch_bounds__(512) void gat_pool(const bf16* __restrict__ rep,
    const int* __restrict__ offs_h, const unsigned char* __restrict__ srcs_h,
    const int* __restrict__ offs_t, const unsigned char* __restrict__ srcs_t,
    const bf16* __restrict__ Wtp, const float* __restrict__ sm,
    void* out, const int* __restrict__ fp){
  __shared__ char U[34816];          // WtL 32 KB then Pm 34 KB
  __shared__ bf16 Ft[64*136];
  __shared__ float attL[384];        // 0-127 att_ps, 128-255 att_pd, 256-383 bias
  __shared__ float2 aSp[128], aDp[128];
  __shared__ float rsum[128];
  __shared__ unsigned char ss[EMAX];
  __shared__ int begs[129];
  int side = blockIdx.y, g = blockIdx.x, t = threadIdx.x;
  int f = *fp;
  const int* offs = side ? offs_t : offs_h;
  const unsigned char* srcs = side ? srcs_t : srcs_h;
  const unsigned short* A = (const unsigned short*)rep + (size_t)side*NN*128;
  size_t obase = (size_t)side*NN*128;
  size_t gbase = (size_t)2*NN*128 + (size_t)side*NG*128;

  bf16* WtL = (bf16*)U;
  {
    const short8v* src = (const short8v*)Wtp;
    short8v* dst = (short8v*)WtL;
    #pragma unroll
    for (int i=0;i<4;i++) dst[t + i*512] = src[t + i*512];
  }
  if (t < 129) begs[t] = offs[g*128 + t];
  if (t < 384) attL[t] = sm[(t<128) ? 192+t : (t<256) ? 320+(t-128) : 576+(t-256)];
  __syncthreads();
  int gbeg = begs[0], Eg = min(begs[128]-gbeg, EMAX);
  for (int i=t; i<Eg; i+=512) ss[i] = srcs[gbeg + i];

  int w = t>>6, l = t&63, lr = l&15, lg = l>>4;
  size_t row = (size_t)g*128 + w*16 + lr;
  f32x4 acc[8];
  #pragma unroll
  for (int nt=0;nt<8;nt++) acc[nt] = (f32x4){0.f,0.f,0.f,0.f};
  #pragma unroll
  for (int ks=0;ks<4;ks++){
    short8v af = *(const short8v*)(A + row*128 + ks*32 + lg*8);
    #pragma unroll
    for (int nt=0;nt<8;nt++){
      short8v bfr = *(const short8v*)((const unsigned short*)WtL + (size_t)((nt*4+ks)*64 + l)*8);
      acc[nt] = __builtin_amdgcn_mfma_f32_16x16x32_bf16(af, bfr, acc[nt], 0, 0, 0);
    }
  }
  // logits: c = nt*16+lr (0..127); head = c>>6 (nt<4 head0); tables indexed by c
  #pragma unroll
  for (int rg=0; rg<4; ++rg){
    float pS0=0.f,pS1=0.f,pD0=0.f,pD1=0.f;
    #pragma unroll
    for (int nt=0;nt<8;nt++){
      float v = acc[nt][rg];
      int c = nt*16 + lr;
      float a = attL[c], b = attL[128+c];
      if (nt<4){ pS0 += v*a; pD0 += v*b; } else { pS1 += v*a; pD1 += v*b; }
    }
    #pragma unroll
    for (int o=1;o<16;o<<=1){
      pS0+=__shfl_xor(pS0,o); pS1+=__shfl_xor(pS1,o);
      pD0+=__shfl_xor(pD0,o); pD1+=__shfl_xor(pD1,o);
    }
    if (lr == 0){
      int rr = w*16 + lg*4 + rg;
      aSp[rr] = make_float2(pS0, pS1);
      aDp[rr] = make_float2(pD0, pD1);
    }
  }
  __syncthreads();   // aSp/aDp/ss ready; WtL dead

  bf16* Pm = (bf16*)U;
  #pragma unroll
  for (int h=0; h<2; ++h){
    for (int i=t; i<128*68; i+=512) ((unsigned int*)Pm)[i] = 0;
    // Ft from acc regs: head h -> nt {4h..4h+3}; c_local = ntl*16+lr
    #pragma unroll
    for (int ntl=0; ntl<4; ++ntl){
      int nt = h*4 + ntl;
      #pragma unroll
      for (int rg=0; rg<4; ++rg)
        ((unsigned short*)Ft)[(ntl*16+lr)*136 + (w*16+lg*4+rg)] = f2bu(acc[nt][rg]);
    }
    __syncthreads();
    if (t < 128){
      int r = t;
      float ad = h ? aDp[r].y : aDp[r].x;
      int b = begs[r]-gbeg, e = min(begs[r+1]-gbeg, EMAX);
      float rs = 0.f;
      unsigned short* Pr = (unsigned short*)Pm + r*136;
      for (int j=b; j<e; ++j){
        int s = ss[j];
        float as = h ? aSp[s].y : aSp[s].x;
        float p = __expf(lrelu(as + ad));
        bf16 ov; *(unsigned short*)&ov = Pr[s];
        Pr[s] = f2bu(b2f(ov) + p);
        rs += p;
      }
      { // self-loops (pool GAT has them)
        float as = h ? aSp[r].y : aSp[r].x;
        float p = __expf(lrelu(as + ad));
        bf16 ov; *(unsigned short*)&ov = Pr[r];
        Pr[r] = f2bu(b2f(ov) + p);
        rs += p;
      }
      rsum[r] = rs;
    }
    __syncthreads();
    // PV: NT=4 per head
    f32x4 a2[4];
    #pragma unroll
    for (int j=0;j<4;j++) a2[j] = (f32x4){0.f,0.f,0.f,0.f};
    #pragma unroll
    for (int ks=0;ks<4;ks++){
      short8v af = *(const short8v*)((const unsigned short*)Pm + (w*16+lr)*136 + ks*32 + lg*8);
      #pragma unroll
      for (int j=0;j<4;j++){
        short8v bfr = *(const short8v*)((const unsigned short*)Ft + (j*16+lr)*136 + ks*32 + lg*8);
        a2[j] = __builtin_amdgcn_mfma_f32_16x16x32_bf16(af, bfr, a2[j], 0, 0, 0);
      }
    }
    #pragma unroll
    for (int rg=0; rg<4; ++rg){
      int rrow = w*16 + lg*4 + rg;
      float rinv = 1.f / (rsum[rrow] + 1e-16f);
      size_t n = (size_t)g*128 + rrow;
      bool gw = (rrow == 127);
      #pragma unroll
      for (int j=0;j<4;j++){
        int c = h*64 + j*16 + lr;
        float o = a2[j][rg]*rinv + attL[256+c];
        size_t oi = obase + n*128 + c;
        if (f){
          ((float*)out)[oi] = o;
          if (gw) ((float*)out)[gbase + (size_t)g*128 + c] = o;
        } else {
          ((bf16*)out)[oi] = f2b(o);
          if (gw) ((bf16*)out)[gbase + (size_t)g*128 + c] = f2b(o);
        }
      }
    }
    __syncthreads();
  }
}

// ---------------- graph LayerNorm + ELU, single-pass, ws-resident rep ----------------
__global__ __launch_bounds__(512) void graph_ln_w(bf16* __restrict__ R_,
    const float* __restrict__ wv, const float* __restrict__ bv){
  __shared__ float sh1[8], sh2[8];
  int g = blockIdx.x, t = threadIdx.x;
  unsigned short* Ru = (unsigned short*)(R_ + (size_t)g*16384);
  short8v v[4];
  #pragma unroll
  for (int q=0;q<4;q++) v[q] = *(short8v*)(Ru + q*4096 + t*8);
  float s1=0.f, s2=0.f;
  #pragma unroll
  for (int q=0;q<4;q++)
    #pragma unroll
    for (int j=0;j<8;j++){
      bf16 b; *(unsigned short*)&b = ((unsigned short*)&v[q])[j];
      float x = b2f(b); s1 += x; s2 += x*x;
    }
  #pragma unroll
  for (int o=32;o;o>>=1){ s1 += __shfl_xor(s1,o); s2 += __shfl_xor(s2,o); }
  if ((t&63)==0){ sh1[t>>6]=s1; sh2[t>>6]=s2; }
  __syncthreads();
  float S1=0.f,S2=0.f;
  #pragma unroll
  for (int i=0;i<8;i++){ S1+=sh1[i]; S2+=sh2[i]; }
  float mean = S1 * (1.f/16384.f);
  float var = fmaxf(S2*(1.f/16384.f) - mean*mean, 0.f);
  float rstd = rsqrtf(var + 1e-5f);
  #pragma unroll
  for (int q=0;q<4;q++){
    short8v ov;
    #pragma unroll
    for (int j=0;j<8;j++){
      int c = (t*8 + j) & 127;
      bf16 b; *(unsigned short*)&b = ((unsigned short*)&v[q])[j];
      float y = (b2f(b)-mean)*rstd*wv[c] + bv[c];
      ((unsigned short*)&ov)[j] = f2bu(y>0.f ? y : expm1f(y));
    }
    *(short8v*)(Ru + q*4096 + t*8) = ov;
  }
}

extern "C" void kernel_launch(void* const* d_in, const int* in_sizes, int n_in,
                              void* d_out, int out_size, void* d_ws, size_t ws_size,
                              hipStream_t stream){
  (void)in_sizes; (void)n_in; (void)out_size; (void)ws_size;
  const void* h_x = d_in[0];
  const void* t_x = d_in[1];
  const int* h_ei = (const int*)d_in[2];
  const int* t_ei = (const int*)d_in[3];
  const int* b_ei = (const int*)d_in[4];

  // ---- workspace (~86 MB; < 96.7 MB proven round 4) ----
  char* base = (char*)d_ws;
  size_t off = 0;
  auto alloc = [&](size_t bytes)->char*{ char* p = base + off; off += (bytes + 255) & ~(size_t)255; return p; };
  bf16* rep      = (bf16*)alloc((size_t)2*NN*128*2);   // rep_h | rep_t (layer-1 out -> LN -> pool in)
  unsigned short* pk = (unsigned short*)alloc((size_t)4*NE*2);
  unsigned char* srcs8 = (unsigned char*)alloc((size_t)4*NE);
  int* offs4     = (int*)alloc((size_t)4*(NN+1)*4);
  int* Hb        = (int*)alloc((size_t)4*NB*NG*4);
  int* Bb        = (int*)alloc((size_t)4*NB*NG*4);
  int* base_gs   = (int*)alloc((size_t)4*(NG+1)*4);
  float* aDx_h   = (float*)alloc((size_t)NN*2*4);
  float* aDx_t   = (float*)alloc((size_t)NN*2*4);
  bf16* Wtc      = (bf16*)alloc(16384*2);
  bf16* Wtp      = (bf16*)alloc(16384*2);
  float* vdst    = (float*)alloc(256*4);
  float* sm      = (float*)alloc(960*4);
  int* flag      = (int*)alloc(256);

  bf16* rep_h = rep;
  bf16* rep_t = rep + (size_t)NN*128;

  detect_dtype<<<1,64,0,stream>>>((const unsigned short*)h_x, flag);

  EPtrs ep;
  ep.s0 = h_ei;      ep.d0 = h_ei + NE;
  ep.s1 = t_ei;      ep.d1 = t_ei + NE;
  ep.s2 = b_ei;      ep.d2 = b_ei + NE;
  ep.s3 = b_ei + NE; ep.d3 = b_ei;
  hist_bagg<<<dim3(NB,4),256,0,stream>>>(ep, Hb);
  scan_bagg<<<4,1024,0,stream>>>(Hb, Bb, base_gs);
  scatter_bagg<<<dim3(NB,4),256,0,stream>>>(ep, Bb, pk);
  build_csr<<<dim3(NG,4),256,0,stream>>>(pk, base_gs, srcs8, offs4);

  prep_kernel<<<1,256,0,stream>>>(d_in[9], d_in[13], d_in[14], d_in[16], d_in[18],
      d_in[10], d_in[11], d_in[15], d_in[19], d_in[20],
      d_in[12], d_in[17], d_in[21], d_in[22], d_in[23],
      Wtc, Wtp, vdst, sm, flag);

  avec_dx_m<<<65536,256,0,stream>>>(h_x, t_x, vdst, aDx_h, aDx_t, flag);

  const int* offs_h = offs4;
  const int* offs_t = offs4 + (NN+1);
  const int* offs_ht= offs4 + 2*(NN+1);
  const int* offs_th= offs4 + 3*(NN+1);
  const unsigned char* srcs_h = srcs8;
  const unsigned char* srcs_t = srcs8 + NE;
  const unsigned char* srcs_ht= srcs8 + (size_t)2*NE;
  const unsigned char* srcs_th= srcs8 + (size_t)3*NE;

  // ---- layer-1: fused quarter-GEMM + GAT, 4 sets, one dispatch ----
  {
    L1Set4 L;
    L.s[0] = { offs_h,  srcs_h,  0, 0, 0, 0,  nullptr, rep_h };
    L.s[1] = { offs_t,  srcs_t,  1, 0, 0, 0,  nullptr, rep_t };
    L.s[2] = { offs_ht, srcs_ht, 0, 1, 1, 64, aDx_t,   rep_t };
    L.s[3] = { offs_th, srcs_th, 1, 1, 1, 64, aDx_h,   rep_h };
    gat_l1<<<dim3(NG,4),512,0,stream>>>(L, h_x, t_x, Wtc, sm, flag);
  }

  // ---- graph LayerNorm + ELU in place on ws rep (both sides) ----
  graph_ln_w<<<2048,512,0,stream>>>(rep, sm+704, sm+832);

  // ---- pool: fused GEMM + GAT -> d_out + gathers ----
  gat_pool<<<dim3(NG,2),512,0,stream>>>(rep, offs_h, srcs_h, offs_t, srcs_t,
      Wtp, sm, d_out, flag);
}